// Round 1
// baseline (134.352 us; speedup 1.0000x reference)
//
#include <hip/hip_runtime.h>
#include <stdint.h>

#define N_NODES 8192
#define N_EDGES 8192
#define DIM 128
#define NL 17                     // MAX_L + 1
#define BM_WORDS (N_NODES / 32)   // 256 bitmap words per edge

// ---- workspace layout (bytes) ----
#define WS_BITMAP_OFF 0
#define WS_BITMAP_SZ ((size_t)N_EDGES * BM_WORDS * sizeof(uint32_t))  // 8 MB
#define WS_PARTIAL_OFF (WS_BITMAP_OFF + WS_BITMAP_SZ)
#define WS_PARTIAL_SZ ((size_t)64 * DIM * sizeof(float))              // 32 KB
#define WS_C0E_OFF (WS_PARTIAL_OFF + WS_PARTIAL_SZ)
#define WS_C0E_SZ ((size_t)NL * DIM * sizeof(float))                  // 8.5 KB

// Column partial sums of x: 64 blocks x 128 rows each.
__global__ __launch_bounds__(128) void k_colsum(const float* __restrict__ x,
                                                float* __restrict__ partial) {
  const int d = threadIdx.x;
  const int b = blockIdx.x;            // 0..63
  const int rows = N_NODES / 64;       // 128
  float s = 0.f;
  const float* p = x + (size_t)b * rows * DIM + d;
#pragma unroll 4
  for (int i = 0; i < rows; ++i) s += p[(size_t)i * DIM];
  partial[b * DIM + d] = s;
}

// c0e[l][j] = sum_i x0[i]*W[0,l,i,j] + B[l,j]  (l = 0..16). c0e[1] doubles as
// the node-side constant (x0 @ W[0,1] + B[1]).
__global__ __launch_bounds__(128) void k_c0e(const float* __restrict__ partial,
                                             const float* __restrict__ W,
                                             const float* __restrict__ Bb,
                                             float* __restrict__ c0e) {
  __shared__ float x0[DIM];
  const int j = threadIdx.x;
  float s = 0.f;
  for (int b = 0; b < 64; ++b) s += partial[b * DIM + j];
  x0[j] = s * (1.0f / N_NODES);
  __syncthreads();
  const int l = blockIdx.x;            // 0..16
  const float* W0l = W + (size_t)l * DIM * DIM;   // W[0][l]
  float acc = Bb[l * DIM + j];
#pragma unroll 8
  for (int i = 0; i < DIM; ++i) acc += x0[i] * W0l[(size_t)i * DIM + j];
  c0e[l * DIM + j] = acc;
}

// Streaming scan of incidence (268 MB, coalesced float4). ~1% nonzero ->
// set bit n in edge e's bitmap. atomicOr => deterministic bitmap.
__global__ __launch_bounds__(256) void k_scan(const float4* __restrict__ inc4,
                                              uint32_t* __restrict__ bitmap) {
  const size_t total = (size_t)N_NODES * N_EDGES / 4;
  const size_t stride = (size_t)gridDim.x * blockDim.x;
  for (size_t i = (size_t)blockIdx.x * blockDim.x + threadIdx.x; i < total;
       i += stride) {
    float4 v = inc4[i];
    if (v.x == 0.f && v.y == 0.f && v.z == 0.f && v.w == 0.f) continue;
    size_t f = i * 4;
    int n = (int)(f >> 13);             // f / N_EDGES
    int e = (int)(f & (N_EDGES - 1));   // f % N_EDGES (4 consecutive e, same n)
    uint32_t bit = 1u << (n & 31);
    int w = n >> 5;
    if (v.x != 0.f) atomicOr(&bitmap[(size_t)(e + 0) * BM_WORDS + w], bit);
    if (v.y != 0.f) atomicOr(&bitmap[(size_t)(e + 1) * BM_WORDS + w], bit);
    if (v.z != 0.f) atomicOr(&bitmap[(size_t)(e + 2) * BM_WORDS + w], bit);
    if (v.w != 0.f) atomicOr(&bitmap[(size_t)(e + 3) * BM_WORDS + w], bit);
  }
}

// Per-edge: compact bitmap -> ordered node list (deterministic), gather+sum
// x rows, normalize, then fused matvec with W[1, order] + c0e[order].
__global__ __launch_bounds__(128) void k_edge(const float* __restrict__ x,
                                              const uint32_t* __restrict__ bitmap,
                                              const int* __restrict__ orders,
                                              const float* __restrict__ norm,
                                              const float* __restrict__ W,
                                              const float* __restrict__ c0e,
                                              float* __restrict__ out_e) {
  __shared__ unsigned short list[512];
  __shared__ int cnts[128];
  __shared__ int total;
  __shared__ float xl[DIM];
  const int t = threadIdx.x;
  const int e = blockIdx.x;
  const uint32_t w0 = bitmap[(size_t)e * BM_WORDS + 2 * t];
  const uint32_t w1 = bitmap[(size_t)e * BM_WORDS + 2 * t + 1];
  cnts[t] = __popc(w0) + __popc(w1);
  __syncthreads();
  if (t == 0) {
    int run = 0;
    for (int i = 0; i < 128; ++i) { int c = cnts[i]; cnts[i] = run; run += c; }
    total = run;
  }
  __syncthreads();
  int base = cnts[t];
  uint32_t m = w0;
  while (m) {
    int b = __ffs(m) - 1;
    if (base < 512) list[base] = (unsigned short)(t * 64 + b);
    ++base; m &= m - 1;
  }
  m = w1;
  while (m) {
    int b = __ffs(m) - 1;
    if (base < 512) list[base] = (unsigned short)(t * 64 + 32 + b);
    ++base; m &= m - 1;
  }
  __syncthreads();
  const int cnt = total < 512 ? total : 512;
  float acc = 0.f;
#pragma unroll 4
  for (int i = 0; i < cnt; ++i) {
    int n = list[i];                        // LDS broadcast
    acc += x[(size_t)n * DIM + t];          // coalesced 512B row gather (L2-hot)
  }
  xl[t] = acc / norm[e];
  __syncthreads();
  const int l = orders[e];
  const float* W1l = W + (size_t)(NL + l) * DIM * DIM;   // W[1][l]
  float o = c0e[l * DIM + t];
#pragma unroll 8
  for (int i = 0; i < DIM; ++i) o += xl[i] * W1l[(size_t)i * DIM + t];
  out_e[(size_t)e * DIM + t] = o;
}

// Node side: out_v[n] = c0e[1] + x[n] @ W[1,1]. 4x4 register tile per thread.
__global__ __launch_bounds__(256) void k_node(const float* __restrict__ x,
                                              const float* __restrict__ W,
                                              const float* __restrict__ c0e,
                                              float* __restrict__ out_v) {
  __shared__ float xr[32][DIM];      // 16 KB: 32 rows of x
  const int t = threadIdx.x;
  const int row0 = blockIdx.x * 32;
  for (int i = t; i < 32 * DIM; i += 256)
    xr[i >> 7][i & 127] = x[(size_t)row0 * DIM + i];
  const int tx = t & 31;             // cols tx*4 .. tx*4+3
  const int ty = t >> 5;             // rows ty*4 .. ty*4+3
  const float4* W4 = (const float4*)(W + (size_t)(NL + 1) * DIM * DIM);  // W[1][1]
  const float4 cv = ((const float4*)(c0e + DIM))[tx];                    // c0e[1]
  float4 o0 = cv, o1 = cv, o2 = cv, o3 = cv;
  __syncthreads();
#pragma unroll 4
  for (int k = 0; k < DIM; ++k) {
    float4 w = W4[k * 32 + tx];      // L1/L2-hot, coalesced
    float a0 = xr[ty * 4 + 0][k];    // LDS broadcast per half-wave
    float a1 = xr[ty * 4 + 1][k];
    float a2 = xr[ty * 4 + 2][k];
    float a3 = xr[ty * 4 + 3][k];
    o0.x += a0 * w.x; o0.y += a0 * w.y; o0.z += a0 * w.z; o0.w += a0 * w.w;
    o1.x += a1 * w.x; o1.y += a1 * w.y; o1.z += a1 * w.z; o1.w += a1 * w.w;
    o2.x += a2 * w.x; o2.y += a2 * w.y; o2.z += a2 * w.z; o2.w += a2 * w.w;
    o3.x += a3 * w.x; o3.y += a3 * w.y; o3.z += a3 * w.z; o3.w += a3 * w.w;
  }
  float4* out4 = (float4*)(out_v + (size_t)(row0 + ty * 4) * DIM);
  out4[0 * 32 + tx] = o0;
  out4[1 * 32 + tx] = o1;
  out4[2 * 32 + tx] = o2;
  out4[3 * 32 + tx] = o3;
}

extern "C" void kernel_launch(void* const* d_in, const int* in_sizes, int n_in,
                              void* d_out, int out_size, void* d_ws, size_t ws_size,
                              hipStream_t stream) {
  const float* x      = (const float*)d_in[0];
  const float* inc    = (const float*)d_in[1];
  const int*   orders = (const int*)d_in[2];
  const float* norm   = (const float*)d_in[3];
  const float* W      = (const float*)d_in[4];
  const float* Bb     = (const float*)d_in[5];
  float* out_v = (float*)d_out;
  float* out_e = (float*)d_out + (size_t)N_NODES * DIM;

  char* ws = (char*)d_ws;
  uint32_t* bitmap = (uint32_t*)(ws + WS_BITMAP_OFF);
  float* partial   = (float*)(ws + WS_PARTIAL_OFF);
  float* c0e       = (float*)(ws + WS_C0E_OFF);

  hipMemsetAsync(bitmap, 0, WS_BITMAP_SZ, stream);
  k_colsum<<<64, 128, 0, stream>>>(x, partial);
  k_c0e<<<NL, 128, 0, stream>>>(partial, W, Bb, c0e);
  k_scan<<<2048, 256, 0, stream>>>((const float4*)inc, bitmap);
  k_edge<<<N_EDGES, 128, 0, stream>>>(x, bitmap, orders, norm, W, c0e, out_e);
  k_node<<<N_NODES / 32, 256, 0, stream>>>(x, W, c0e, out_v);
}

// Round 2
// 124.690 us; speedup vs baseline: 1.0775x; 1.0775x over previous
//
#include <hip/hip_runtime.h>
#include <stdint.h>

#define NN 8192   // nodes
#define NE 8192   // edges
#define DIM 128
#define NL 17
#define SPLITK 8
#define KCHUNK (NN / SPLITK)   // 1024

typedef float f32x4 __attribute__((ext_vector_type(4)));
typedef short short8 __attribute__((ext_vector_type(8)));

// ---- workspace layout (bytes) ----
#define WS_XHI    0ull                             // 2 MB  (xT blocked hi bf16)
#define WS_XLO    (2ull << 20)                     // 2 MB  (xT blocked lo bf16)
#define WS_COLSUM (4ull << 20)                     // 64 KB (128 x 128 f32)
#define WS_C0E    ((4ull << 20) + 128 * 128 * 4)   // 8.5 KB
#define WS_PART   (8ull << 20)                     // 32 MB (SPLITK x E x D f32)

// Round-to-nearest-even f32 -> bf16 bits.
__device__ __forceinline__ uint16_t f32_to_bf16(float v) {
  uint32_t u = __builtin_bit_cast(uint32_t, v);
  u += 0x7fffu + ((u >> 16) & 1u);
  return (uint16_t)(u >> 16);
}
__device__ __forceinline__ float bf16_to_f32(uint16_t h) {
  uint32_t u = ((uint32_t)h) << 16;
  return __builtin_bit_cast(float, u);
}

// Prep: column sums of x (for x0), and x transposed into k-blocked bf16 hi/lo:
// xTb[kblk][d][kk] with kblk = k/32, kk = k%32. 128 blocks x 64 nodes.
__global__ __launch_bounds__(256) void k_prep(const float* __restrict__ x,
                                              uint16_t* __restrict__ xhi,
                                              uint16_t* __restrict__ xlo,
                                              float* __restrict__ colsum) {
  __shared__ float xs[64][129];
  const int t = threadIdx.x;
  const int b = blockIdx.x;  // nodes b*64 .. b*64+63
  const float4* xg = (const float4*)(x + (size_t)b * 64 * DIM);
  for (int r = 0; r < 8; ++r) {
    int f = t + r * 256;           // float4 index within tile
    float4 v = xg[f];
    int n = f >> 5;
    int d0 = (f & 31) * 4;
    xs[n][d0] = v.x; xs[n][d0 + 1] = v.y; xs[n][d0 + 2] = v.z; xs[n][d0 + 3] = v.w;
  }
  __syncthreads();
  if (t < 128) {
    float s = 0.f;
    for (int n = 0; n < 64; ++n) s += xs[n][t];
    colsum[b * DIM + t] = s;
  }
  // 2048 16B chunks: q = [hl(1)][kb(1)][d(7)][c(2)]
  for (int r = 0; r < 8; ++r) {
    int q = t + r * 256;
    int c = q & 3;
    int d = (q >> 2) & 127;
    int kb = (q >> 9) & 1;
    int hl = q >> 10;
    int kk0 = c * 8;
    uint32_t w[4];
    for (int j = 0; j < 4; ++j) {
      uint16_t h0, h1;
      {
        float v = xs[kb * 32 + kk0 + 2 * j][d];
        uint16_t hi = f32_to_bf16(v);
        h0 = hl ? f32_to_bf16(v - bf16_to_f32(hi)) : hi;
      }
      {
        float v = xs[kb * 32 + kk0 + 2 * j + 1][d];
        uint16_t hi = f32_to_bf16(v);
        h1 = hl ? f32_to_bf16(v - bf16_to_f32(hi)) : hi;
      }
      w[j] = (uint32_t)h0 | ((uint32_t)h1 << 16);
    }
    int kblk = b * 2 + kb;
    uint16_t* dst = (hl ? xlo : xhi) + ((size_t)(kblk * 128 + d)) * 32 + kk0;
    *(uint4*)dst = make_uint4(w[0], w[1], w[2], w[3]);
  }
}

// c0e[l][j] = x0 @ W[0,l] + B[l]; c0e[1] doubles as node-side constant.
__global__ __launch_bounds__(128) void k_c0e(const float* __restrict__ colsum,
                                             const float* __restrict__ W,
                                             const float* __restrict__ Bb,
                                             float* __restrict__ c0e) {
  __shared__ float x0[DIM];
  const int j = threadIdx.x;
  float s = 0.f;
  for (int b = 0; b < 128; ++b) s += colsum[b * DIM + j];
  x0[j] = s * (1.0f / NN);
  __syncthreads();
  const int l = blockIdx.x;
  const float* W0l = W + (size_t)l * DIM * DIM;
  float acc = Bb[l * DIM + j];
#pragma unroll 8
  for (int i = 0; i < DIM; ++i) acc += x0[i] * W0l[(size_t)i * DIM + j];
  c0e[l * DIM + j] = acc;
}

// Big MFMA GEMM: part[s][e][d] = sum_{k in chunk s} inc[k][e] * x[k][d].
// A (inc) direct-from-global in fragment layout, packed f32->bf16 (exact for 0/1).
// B (x hi/lo bf16) staged in LDS with 40-elem padded rows.
__global__ __launch_bounds__(256) void k_gemm(const float* __restrict__ inc,
                                              const uint16_t* __restrict__ xhi,
                                              const uint16_t* __restrict__ xlo,
                                              float* __restrict__ part) {
  __shared__ uint16_t Bh[128 * 40];
  __shared__ uint16_t Bl[128 * 40];
  const int t = threadIdx.x;
  const int mb = blockIdx.x & 63;
  const int s = blockIdx.x >> 6;
  const int e0 = mb * 128;
  const int w = t >> 6;
  const int lane = t & 63;
  const int lm = lane & 15;
  const int lk = lane >> 4;          // 0..3
  f32x4 acc[2][8];
  for (int a = 0; a < 2; ++a)
    for (int b = 0; b < 8; ++b) acc[a][b] = (f32x4){0.f, 0.f, 0.f, 0.f};
  const int kbase = s * KCHUNK;
  for (int it = 0; it < KCHUNK / 32; ++it) {
    const int k0 = kbase + it * 32;
    const int kblk = k0 >> 5;
    // stage B: 1024 16B chunks: q = [hl(1)][d(7)][c(2)]
    for (int r = 0; r < 4; ++r) {
      int q = t + r * 256;
      int c = q & 3;
      int d = (q >> 2) & 127;
      int hl = q >> 9;
      const uint16_t* src =
          (hl ? xlo : xhi) + ((size_t)(kblk * 128 + d)) * 32 + c * 8;
      uint4 v = *(const uint4*)src;
      uint16_t* dst = (hl ? Bl : Bh) + d * 40 + c * 8;
      *(uint4*)dst = v;
    }
    __syncthreads();
    // A fragments: lane lm -> row m, lk -> k-subchunk
    short8 afr[2];
    for (int fm = 0; fm < 2; ++fm) {
      int m = e0 + w * 32 + fm * 16 + lm;
      const float* ap = inc + (size_t)(k0 + lk * 8) * NE + m;
      uint32_t u[8];
#pragma unroll
      for (int j = 0; j < 8; ++j)
        u[j] = __builtin_bit_cast(uint32_t, ap[(size_t)j * NE]);
      union { uint32_t w4[4]; short8 s8; } pk;
#pragma unroll
      for (int j = 0; j < 4; ++j)
        pk.w4[j] = (u[2 * j + 1] & 0xffff0000u) | (u[2 * j] >> 16);
      afr[fm] = pk.s8;
    }
#pragma unroll
    for (int fn = 0; fn < 8; ++fn) {
      int n = fn * 16 + lm;
      short8 bh = *(const short8*)(Bh + n * 40 + lk * 8);
      short8 bl = *(const short8*)(Bl + n * 40 + lk * 8);
#pragma unroll
      for (int fm = 0; fm < 2; ++fm) {
        acc[fm][fn] = __builtin_amdgcn_mfma_f32_16x16x32_bf16(afr[fm], bh, acc[fm][fn], 0, 0, 0);
        acc[fm][fn] = __builtin_amdgcn_mfma_f32_16x16x32_bf16(afr[fm], bl, acc[fm][fn], 0, 0, 0);
      }
    }
    __syncthreads();
  }
  float* pbase = part + (size_t)s * NE * DIM;
  for (int fm = 0; fm < 2; ++fm)
    for (int fn = 0; fn < 8; ++fn)
      for (int r = 0; r < 4; ++r) {
        int e = e0 + w * 32 + fm * 16 + lk * 4 + r;
        int d = fn * 16 + lm;
        pbase[(size_t)e * DIM + d] = acc[fm][fn][r];
      }
}

// Per-edge: reduce split-K partials, normalize, matvec with W[1,order] + c0e.
__global__ __launch_bounds__(128) void k_edge2(const float* __restrict__ part,
                                               const int* __restrict__ orders,
                                               const float* __restrict__ norm,
                                               const float* __restrict__ W,
                                               const float* __restrict__ c0e,
                                               float* __restrict__ out_e) {
  __shared__ float xl[DIM];
  const int t = threadIdx.x;
  const int e = blockIdx.x;
  float s = 0.f;
#pragma unroll
  for (int k = 0; k < SPLITK; ++k)
    s += part[(size_t)k * NE * DIM + (size_t)e * DIM + t];
  xl[t] = s / norm[e];
  __syncthreads();
  const int l = orders[e];
  const float* W1l = W + (size_t)(NL + l) * DIM * DIM;
  float o = c0e[l * DIM + t];
#pragma unroll 8
  for (int i = 0; i < DIM; ++i) o += xl[i] * W1l[(size_t)i * DIM + t];
  out_e[(size_t)e * DIM + t] = o;
}

// Node side: out_v[n] = c0e[1] + x[n] @ W[1,1]. 4x4 register tile per thread.
__global__ __launch_bounds__(256) void k_node(const float* __restrict__ x,
                                              const float* __restrict__ W,
                                              const float* __restrict__ c0e,
                                              float* __restrict__ out_v) {
  __shared__ float xr[32][DIM];
  const int t = threadIdx.x;
  const int row0 = blockIdx.x * 32;
  for (int i = t; i < 32 * DIM; i += 256)
    xr[i >> 7][i & 127] = x[(size_t)row0 * DIM + i];
  const int tx = t & 31;
  const int ty = t >> 5;
  const float4* W4 = (const float4*)(W + (size_t)(NL + 1) * DIM * DIM);
  const float4 cv = ((const float4*)(c0e + DIM))[tx];
  float4 o0 = cv, o1 = cv, o2 = cv, o3 = cv;
  __syncthreads();
#pragma unroll 4
  for (int k = 0; k < DIM; ++k) {
    float4 w = W4[k * 32 + tx];
    float a0 = xr[ty * 4 + 0][k];
    float a1 = xr[ty * 4 + 1][k];
    float a2 = xr[ty * 4 + 2][k];
    float a3 = xr[ty * 4 + 3][k];
    o0.x += a0 * w.x; o0.y += a0 * w.y; o0.z += a0 * w.z; o0.w += a0 * w.w;
    o1.x += a1 * w.x; o1.y += a1 * w.y; o1.z += a1 * w.z; o1.w += a1 * w.w;
    o2.x += a2 * w.x; o2.y += a2 * w.y; o2.z += a2 * w.z; o2.w += a2 * w.w;
    o3.x += a3 * w.x; o3.y += a3 * w.y; o3.z += a3 * w.z; o3.w += a3 * w.w;
  }
  float4* out4 = (float4*)(out_v + (size_t)(row0 + ty * 4) * DIM);
  out4[0 * 32 + tx] = o0;
  out4[1 * 32 + tx] = o1;
  out4[2 * 32 + tx] = o2;
  out4[3 * 32 + tx] = o3;
}

extern "C" void kernel_launch(void* const* d_in, const int* in_sizes, int n_in,
                              void* d_out, int out_size, void* d_ws, size_t ws_size,
                              hipStream_t stream) {
  const float* x      = (const float*)d_in[0];
  const float* inc    = (const float*)d_in[1];
  const int*   orders = (const int*)d_in[2];
  const float* norm   = (const float*)d_in[3];
  const float* W      = (const float*)d_in[4];
  const float* Bb     = (const float*)d_in[5];
  float* out_v = (float*)d_out;
  float* out_e = (float*)d_out + (size_t)NN * DIM;

  char* ws = (char*)d_ws;
  uint16_t* xhi   = (uint16_t*)(ws + WS_XHI);
  uint16_t* xlo   = (uint16_t*)(ws + WS_XLO);
  float* colsum   = (float*)(ws + WS_COLSUM);
  float* c0e      = (float*)(ws + WS_C0E);
  float* part     = (float*)(ws + WS_PART);

  k_prep<<<128, 256, 0, stream>>>(x, xhi, xlo, colsum);
  k_c0e<<<NL, 128, 0, stream>>>(colsum, W, Bb, c0e);
  k_gemm<<<512, 256, 0, stream>>>(inc, xhi, xlo, part);
  k_edge2<<<NE, 128, 0, stream>>>(part, orders, norm, W, c0e, out_e);
  k_node<<<NN / 32, 256, 0, stream>>>(x, W, c0e, out_v);
}

// Round 3
// 119.097 us; speedup vs baseline: 1.1281x; 1.0470x over previous
//
#include <hip/hip_runtime.h>
#include <stdint.h>

#define NN 8192   // nodes
#define NE 8192   // edges
#define DIM 128
#define NL 17
#define SPLITK 8
#define KCHUNK (NN / SPLITK)   // 1024
#define NIT (KCHUNK / 32)      // 32

typedef float f32x4 __attribute__((ext_vector_type(4)));
typedef short short8 __attribute__((ext_vector_type(8)));

// ---- workspace layout (bytes) ----
#define WS_XHI    0ull                             // 2 MB  (xT blocked hi bf16)
#define WS_XLO    (2ull << 20)                     // 2 MB  (xT blocked lo bf16)
#define WS_COLSUM (4ull << 20)                     // 64 KB (128 x 128 f32)
#define WS_C0E    ((4ull << 20) + 128 * 128 * 4)   // 8.5 KB
#define WS_PART   (8ull << 20)                     // 32 MB (SPLITK x E x D f32)

#define GPTR(p) ((const __attribute__((address_space(1))) uint32_t*)(p))
#define LPTR(p) ((__attribute__((address_space(3))) uint32_t*)(p))

// Round-to-nearest-even f32 -> bf16 bits.
__device__ __forceinline__ uint16_t f32_to_bf16(float v) {
  uint32_t u = __builtin_bit_cast(uint32_t, v);
  u += 0x7fffu + ((u >> 16) & 1u);
  return (uint16_t)(u >> 16);
}
__device__ __forceinline__ float bf16_to_f32(uint16_t h) {
  uint32_t u = ((uint32_t)h) << 16;
  return __builtin_bit_cast(float, u);
}

// Prep: column sums of x (for x0), and x transposed into k-blocked bf16 hi/lo:
// xTb[kblk][d][kk] with kblk = k/32, kk = k%32. 128 blocks x 64 nodes.
__global__ __launch_bounds__(256) void k_prep(const float* __restrict__ x,
                                              uint16_t* __restrict__ xhi,
                                              uint16_t* __restrict__ xlo,
                                              float* __restrict__ colsum) {
  __shared__ float xs[64][129];
  const int t = threadIdx.x;
  const int b = blockIdx.x;  // nodes b*64 .. b*64+63
  const float4* xg = (const float4*)(x + (size_t)b * 64 * DIM);
  for (int r = 0; r < 8; ++r) {
    int f = t + r * 256;           // float4 index within tile
    float4 v = xg[f];
    int n = f >> 5;
    int d0 = (f & 31) * 4;
    xs[n][d0] = v.x; xs[n][d0 + 1] = v.y; xs[n][d0 + 2] = v.z; xs[n][d0 + 3] = v.w;
  }
  __syncthreads();
  if (t < 128) {
    float s = 0.f;
    for (int n = 0; n < 64; ++n) s += xs[n][t];
    colsum[b * DIM + t] = s;
  }
  // 2048 16B chunks: q = [hl(1)][kb(1)][d(7)][c(2)]
  for (int r = 0; r < 8; ++r) {
    int q = t + r * 256;
    int c = q & 3;
    int d = (q >> 2) & 127;
    int kb = (q >> 9) & 1;
    int hl = q >> 10;
    int kk0 = c * 8;
    uint32_t w[4];
    for (int j = 0; j < 4; ++j) {
      uint16_t h0, h1;
      {
        float v = xs[kb * 32 + kk0 + 2 * j][d];
        uint16_t hi = f32_to_bf16(v);
        h0 = hl ? f32_to_bf16(v - bf16_to_f32(hi)) : hi;
      }
      {
        float v = xs[kb * 32 + kk0 + 2 * j + 1][d];
        uint16_t hi = f32_to_bf16(v);
        h1 = hl ? f32_to_bf16(v - bf16_to_f32(hi)) : hi;
      }
      w[j] = (uint32_t)h0 | ((uint32_t)h1 << 16);
    }
    int kblk = b * 2 + kb;
    uint16_t* dst = (hl ? xlo : xhi) + ((size_t)(kblk * 128 + d)) * 32 + kk0;
    *(uint4*)dst = make_uint4(w[0], w[1], w[2], w[3]);
  }
}

// c0e[l][j] = x0 @ W[0,l] + B[l]; c0e[1] doubles as node-side constant.
__global__ __launch_bounds__(128) void k_c0e(const float* __restrict__ colsum,
                                             const float* __restrict__ W,
                                             const float* __restrict__ Bb,
                                             float* __restrict__ c0e) {
  __shared__ float x0[DIM];
  const int j = threadIdx.x;
  float s = 0.f;
  for (int b = 0; b < 128; ++b) s += colsum[b * DIM + j];
  x0[j] = s * (1.0f / NN);
  __syncthreads();
  const int l = blockIdx.x;
  const float* W0l = W + (size_t)l * DIM * DIM;
  float acc = Bb[l * DIM + j];
#pragma unroll 8
  for (int i = 0; i < DIM; ++i) acc += x0[i] * W0l[(size_t)i * DIM + j];
  c0e[l * DIM + j] = acc;
}

// Big MFMA GEMM: part[s][e][d] = sum_{k in chunk s} inc[k][e] * x[k][d].
// Software-pipelined: double-buffered B via global_load_lds(16B), A-register
// prefetch one iteration ahead, one barrier per iteration.
__global__ __launch_bounds__(256, 2) void k_gemm(const float* __restrict__ inc,
                                                 const uint16_t* __restrict__ xhi,
                                                 const uint16_t* __restrict__ xlo,
                                                 float* __restrict__ part) {
  // [buf][hi(0..4095) | lo(4096..8191)], layout hi: d*32+kk (bf16)
  __shared__ uint16_t Bs[2][8192];
  const int t = threadIdx.x;
  const int mb = blockIdx.x & 63;
  const int s = blockIdx.x >> 6;
  const int e0 = mb * 128;
  const int w = t >> 6;
  const int lane = t & 63;
  const int lm = lane & 15;
  const int lk = lane >> 4;          // 0..3
  const int kbase = s * KCHUNK;
  const int kb0 = kbase >> 5;        // first kblk

  f32x4 acc[2][8];
#pragma unroll
  for (int a = 0; a < 2; ++a)
#pragma unroll
    for (int b = 0; b < 8; ++b) acc[a][b] = (f32x4){0.f, 0.f, 0.f, 0.f};

  const char* hbase = (const char*)xhi;
  const char* lbase = (const char*)xlo;

#define STAGE(buf, kblk) { \
    const char* hsrc = hbase + (size_t)(kblk) * 8192; \
    const char* lsrc = lbase + (size_t)(kblk) * 8192; \
    char* dbase = (char*)&Bs[buf][0]; \
    _Pragma("unroll") \
    for (int j = 0; j < 4; ++j) { \
      int q = w + 4 * j; \
      const char* src = (q < 8) ? (hsrc + q * 1024) : (lsrc + (q - 8) * 1024); \
      __builtin_amdgcn_global_load_lds(GPTR(src + lane * 16), \
                                       LPTR(dbase + q * 1024), 16, 0, 0); \
    } }

#define LOADA(u, it) { \
    const int k0_ = kbase + (it) * 32; \
    _Pragma("unroll") \
    for (int fm = 0; fm < 2; ++fm) { \
      const float* ap = inc + (size_t)(k0_ + lk * 8) * NE + (e0 + w * 32 + fm * 16 + lm); \
      _Pragma("unroll") \
      for (int j = 0; j < 8; ++j) \
        u[fm][j] = __builtin_bit_cast(uint32_t, ap[(size_t)j * NE]); \
    } }

#define COMPUTE(buf, u) { \
    short8 afr[2]; \
    _Pragma("unroll") \
    for (int fm = 0; fm < 2; ++fm) { \
      union { uint32_t w4[4]; short8 s8; } pk; \
      _Pragma("unroll") \
      for (int j = 0; j < 4; ++j) \
        pk.w4[j] = (u[fm][2 * j + 1] & 0xffff0000u) | (u[fm][2 * j] >> 16); \
      afr[fm] = pk.s8; \
    } \
    _Pragma("unroll") \
    for (int fn = 0; fn < 8; ++fn) { \
      int n = fn * 16 + lm; \
      short8 bh = *(const short8*)&Bs[buf][n * 32 + lk * 8]; \
      short8 bl = *(const short8*)&Bs[buf][4096 + n * 32 + lk * 8]; \
      acc[0][fn] = __builtin_amdgcn_mfma_f32_16x16x32_bf16(afr[0], bh, acc[0][fn], 0, 0, 0); \
      acc[1][fn] = __builtin_amdgcn_mfma_f32_16x16x32_bf16(afr[1], bh, acc[1][fn], 0, 0, 0); \
      acc[0][fn] = __builtin_amdgcn_mfma_f32_16x16x32_bf16(afr[0], bl, acc[0][fn], 0, 0, 0); \
      acc[1][fn] = __builtin_amdgcn_mfma_f32_16x16x32_bf16(afr[1], bl, acc[1][fn], 0, 0, 0); \
    } }

  uint32_t ua[2][8], ub[2][8];
  STAGE(0, kb0);
  LOADA(ua, 0);
  __syncthreads();               // Bs[0] staged, ua ready

  for (int it2 = 0; it2 < NIT; it2 += 2) {
    // even iteration: compute Bs[0]/ua, prefetch Bs[1]/ub
    if (it2 + 1 < NIT) { STAGE(1, kb0 + it2 + 1); LOADA(ub, it2 + 1); }
    COMPUTE(0, ua);
    __syncthreads();
    // odd iteration: compute Bs[1]/ub, prefetch Bs[0]/ua
    if (it2 + 2 < NIT) { STAGE(0, kb0 + it2 + 2); LOADA(ua, it2 + 2); }
    COMPUTE(1, ub);
    __syncthreads();
  }

  float* pbase = part + (size_t)s * NE * DIM;
#pragma unroll
  for (int fm = 0; fm < 2; ++fm)
#pragma unroll
    for (int fn = 0; fn < 8; ++fn)
#pragma unroll
      for (int r = 0; r < 4; ++r) {
        int e = e0 + w * 32 + fm * 16 + lk * 4 + r;
        int d = fn * 16 + lm;
        pbase[(size_t)e * DIM + d] = acc[fm][fn][r];
      }
#undef STAGE
#undef LOADA
#undef COMPUTE
}

// Per-edge: reduce split-K partials, normalize, matvec with W[1,order] + c0e.
__global__ __launch_bounds__(128) void k_edge2(const float* __restrict__ part,
                                               const int* __restrict__ orders,
                                               const float* __restrict__ norm,
                                               const float* __restrict__ W,
                                               const float* __restrict__ c0e,
                                               float* __restrict__ out_e) {
  __shared__ float xl[DIM];
  const int t = threadIdx.x;
  const int e = blockIdx.x;
  float s = 0.f;
#pragma unroll
  for (int k = 0; k < SPLITK; ++k)
    s += part[(size_t)k * NE * DIM + (size_t)e * DIM + t];
  xl[t] = s / norm[e];
  __syncthreads();
  const int l = orders[e];
  const float* W1l = W + (size_t)(NL + l) * DIM * DIM;
  float o = c0e[l * DIM + t];
#pragma unroll 8
  for (int i = 0; i < DIM; ++i) o += xl[i] * W1l[(size_t)i * DIM + t];
  out_e[(size_t)e * DIM + t] = o;
}

// Node side: out_v[n] = c0e[1] + x[n] @ W[1,1]. 4x4 register tile per thread.
__global__ __launch_bounds__(256) void k_node(const float* __restrict__ x,
                                              const float* __restrict__ W,
                                              const float* __restrict__ c0e,
                                              float* __restrict__ out_v) {
  __shared__ float xr[32][DIM];
  const int t = threadIdx.x;
  const int row0 = blockIdx.x * 32;
  for (int i = t; i < 32 * DIM; i += 256)
    xr[i >> 7][i & 127] = x[(size_t)row0 * DIM + i];
  const int tx = t & 31;
  const int ty = t >> 5;
  const float4* W4 = (const float4*)(W + (size_t)(NL + 1) * DIM * DIM);
  const float4 cv = ((const float4*)(c0e + DIM))[tx];
  float4 o0 = cv, o1 = cv, o2 = cv, o3 = cv;
  __syncthreads();
#pragma unroll 4
  for (int k = 0; k < DIM; ++k) {
    float4 w = W4[k * 32 + tx];
    float a0 = xr[ty * 4 + 0][k];
    float a1 = xr[ty * 4 + 1][k];
    float a2 = xr[ty * 4 + 2][k];
    float a3 = xr[ty * 4 + 3][k];
    o0.x += a0 * w.x; o0.y += a0 * w.y; o0.z += a0 * w.z; o0.w += a0 * w.w;
    o1.x += a1 * w.x; o1.y += a1 * w.y; o1.z += a1 * w.z; o1.w += a1 * w.w;
    o2.x += a2 * w.x; o2.y += a2 * w.y; o2.z += a2 * w.z; o2.w += a2 * w.w;
    o3.x += a3 * w.x; o3.y += a3 * w.y; o3.z += a3 * w.z; o3.w += a3 * w.w;
  }
  float4* out4 = (float4*)(out_v + (size_t)(row0 + ty * 4) * DIM);
  out4[0 * 32 + tx] = o0;
  out4[1 * 32 + tx] = o1;
  out4[2 * 32 + tx] = o2;
  out4[3 * 32 + tx] = o3;
}

extern "C" void kernel_launch(void* const* d_in, const int* in_sizes, int n_in,
                              void* d_out, int out_size, void* d_ws, size_t ws_size,
                              hipStream_t stream) {
  const float* x      = (const float*)d_in[0];
  const float* inc    = (const float*)d_in[1];
  const int*   orders = (const int*)d_in[2];
  const float* norm   = (const float*)d_in[3];
  const float* W      = (const float*)d_in[4];
  const float* Bb     = (const float*)d_in[5];
  float* out_v = (float*)d_out;
  float* out_e = (float*)d_out + (size_t)NN * DIM;

  char* ws = (char*)d_ws;
  uint16_t* xhi   = (uint16_t*)(ws + WS_XHI);
  uint16_t* xlo   = (uint16_t*)(ws + WS_XLO);
  float* colsum   = (float*)(ws + WS_COLSUM);
  float* c0e      = (float*)(ws + WS_C0E);
  float* part     = (float*)(ws + WS_PART);

  k_prep<<<128, 256, 0, stream>>>(x, xhi, xlo, colsum);
  k_c0e<<<NL, 128, 0, stream>>>(colsum, W, Bb, c0e);
  k_gemm<<<512, 256, 0, stream>>>(inc, xhi, xlo, part);
  k_edge2<<<NE, 128, 0, stream>>>(part, orders, norm, W, c0e, out_e);
  k_node<<<NN / 32, 256, 0, stream>>>(x, W, c0e, out_v);
}